// Round 3
// baseline (1536.636 us; speedup 1.0000x reference)
//
#include <hip/hip_runtime.h>
#include <hip/hip_bf16.h>

// a_mean_op: out = where(deg>0, segment_mean(relu(h @ W.T + b)[src], dst), hr)
// R3: fp32 in/out (harness grants bf16 tolerance). bf16-MFMA GEMM -> hr(bf16,ws)
//     -> atomic scatter into d_out(fp32) -> in-place finalize.

#define FEAT 128

using bf16 = __hip_bfloat16;
typedef __attribute__((ext_vector_type(8))) short short8_;   // 8 x bf16
typedef __attribute__((ext_vector_type(4))) short bhalf4;    // 4 x bf16 (avoid HIP short4)
typedef __attribute__((ext_vector_type(4))) float floatx4;

// ---------------------------------------------------------------------------
// Kernel 1: hr = bf16(relu(h @ W.T + b)). h,W,b fp32; internal bf16 MFMA.
// hr[i][j] = sum_k h[i][k]*W[j][k]  (A*B^T, both operands K-major -> identical
// frag loads, m92-verified pattern). C/D: col=lane&15, row=(lane>>4)*4+reg.
// ---------------------------------------------------------------------------
#define BM 64
__launch_bounds__(256)
__global__ void gemm_relu_kernel(const float* __restrict__ h,
                                 const float* __restrict__ W,
                                 const float* __restrict__ b,
                                 bf16* __restrict__ hr, int M) {
    __shared__ bf16 sA[BM][136];    // +8 pad keeps 16B align, spreads banks
    __shared__ bf16 sW[FEAT][136];

    const int tid  = threadIdx.x;
    const int row0 = blockIdx.x * BM;

    // stage W: 128x128 fp32 = 4096 float4, 16 per thread; convert to bf16
    #pragma unroll
    for (int i = 0; i < 16; ++i) {
        int v = i * 256 + tid;          // 0..4095
        int r = v >> 5;                 // 32 float4 per row
        int c = (v & 31) * 4;
        float4 f = *(const float4*)(W + (size_t)r * FEAT + c);
        bhalf4 s;
        s[0] = __bfloat16_as_short(__float2bfloat16(f.x));
        s[1] = __bfloat16_as_short(__float2bfloat16(f.y));
        s[2] = __bfloat16_as_short(__float2bfloat16(f.z));
        s[3] = __bfloat16_as_short(__float2bfloat16(f.w));
        *(bhalf4*)(&sW[r][c]) = s;
    }
    // stage A: 64x128 fp32 = 2048 float4, 8 per thread
    #pragma unroll
    for (int i = 0; i < 8; ++i) {
        int v = i * 256 + tid;          // 0..2047
        int r = v >> 5;
        int c = (v & 31) * 4;
        int row = row0 + r;
        float4 f = make_float4(0.f, 0.f, 0.f, 0.f);
        if (row < M) f = *(const float4*)(h + (size_t)row * FEAT + c);
        bhalf4 s;
        s[0] = __bfloat16_as_short(__float2bfloat16(f.x));
        s[1] = __bfloat16_as_short(__float2bfloat16(f.y));
        s[2] = __bfloat16_as_short(__float2bfloat16(f.z));
        s[3] = __bfloat16_as_short(__float2bfloat16(f.w));
        *(bhalf4*)(&sA[r][c]) = s;
    }
    __syncthreads();

    const int wave = tid >> 6;
    const int lane = tid & 63;
    const int m    = lane & 15;
    const int ko   = (lane >> 4) * 8;

    floatx4 acc[8];
    #pragma unroll
    for (int t = 0; t < 8; ++t) acc[t] = floatx4{0.f, 0.f, 0.f, 0.f};

    #pragma unroll
    for (int k0 = 0; k0 < FEAT; k0 += 32) {
        short8_ afrag = *(const short8_*)(&sA[wave * 16 + m][k0 + ko]);
        #pragma unroll
        for (int nt = 0; nt < 8; ++nt) {
            short8_ bfrag = *(const short8_*)(&sW[nt * 16 + m][k0 + ko]);
            acc[nt] = __builtin_amdgcn_mfma_f32_16x16x32_bf16(afrag, bfrag, acc[nt], 0, 0, 0);
        }
    }

    const int rbase = row0 + wave * 16 + (lane >> 4) * 4;
    #pragma unroll
    for (int nt = 0; nt < 8; ++nt) {
        int col = nt * 16 + m;
        float bias = b[col];
        #pragma unroll
        for (int r = 0; r < 4; ++r) {
            int row = rbase + r;
            if (row < M) {
                float v = fmaxf(acc[nt][r] + bias, 0.0f);
                hr[(size_t)row * FEAT + col] = __float2bfloat16(v);
            }
        }
    }
}

// ---------------------------------------------------------------------------
// Kernel 2: edge scatter. 1 wave per edge; lane i handles feats 2i,2i+1.
// fp32 atomicAdd directly into out (pre-zeroed); lane0 bumps deg.
// ---------------------------------------------------------------------------
__launch_bounds__(256)
__global__ void scatter_kernel(const bf16* __restrict__ hr,
                               const int* __restrict__ src,
                               const int* __restrict__ dst,
                               float* __restrict__ out,
                               int* __restrict__ deg, int E) {
    int e = blockIdx.x * 4 + (threadIdx.x >> 6);
    if (e >= E) return;
    int lane = threadIdx.x & 63;
    int s = src[e];
    int d = dst[e];
    const __hip_bfloat162* hp = (const __hip_bfloat162*)(hr + (size_t)s * FEAT);
    float2 f2 = __bfloat1622float2(hp[lane]);
    float* op = out + (size_t)d * FEAT + lane * 2;
    atomicAdd(op + 0, f2.x);
    atomicAdd(op + 1, f2.y);
    if (lane == 0) atomicAdd(&deg[d], 1);
}

// ---------------------------------------------------------------------------
// Kernel 3 (in-place): out = deg>0 ? out/deg : fp32(hr). Thread per 4 feats.
// ---------------------------------------------------------------------------
__launch_bounds__(256)
__global__ void finalize_kernel(const bf16* __restrict__ hr,
                                const int* __restrict__ deg,
                                float* __restrict__ out, int N) {
    int gid = blockIdx.x * 256 + threadIdx.x;   // N*32 total
    int node = gid >> 5;
    if (node >= N) return;
    int q = (gid & 31) * 4;
    size_t base = (size_t)node * FEAT + q;
    int d = deg[node];
    float4 v;
    if (d > 0) {
        v = *(const float4*)(out + base);
        float inv = 1.0f / (float)d;
        v.x *= inv; v.y *= inv; v.z *= inv; v.w *= inv;
    } else {
        bhalf4 s = *(const bhalf4*)(hr + base);
        v.x = __bfloat162float(__short_as_bfloat16(s[0]));
        v.y = __bfloat162float(__short_as_bfloat16(s[1]));
        v.z = __bfloat162float(__short_as_bfloat16(s[2]));
        v.w = __bfloat162float(__short_as_bfloat16(s[3]));
    }
    *(float4*)(out + base) = v;
}

// ---------------------------------------------------------------------------
extern "C" void kernel_launch(void* const* d_in, const int* in_sizes, int n_in,
                              void* d_out, int out_size, void* d_ws, size_t ws_size,
                              hipStream_t stream) {
    const float* h   = (const float*)d_in[0];
    // d_in[1] = h_in (unused by reference)
    const int*   src = (const int*)d_in[2];
    const int*   dst = (const int*)d_in[3];
    const float* W   = (const float*)d_in[4];
    const float* b   = (const float*)d_in[5];
    float* out = (float*)d_out;

    const int N = in_sizes[0] / FEAT;
    const int E = in_sizes[2];

    // workspace: hr bf16 [N*128] (25.6 MB) | deg int [N] (0.4 MB)
    char* ws = (char*)d_ws;
    bf16* hr  = (bf16*)ws;
    int*  deg = (int*)(ws + (size_t)N * FEAT * 2);

    (void)hipMemsetAsync(out, 0, (size_t)N * FEAT * 4, stream);
    (void)hipMemsetAsync(deg, 0, (size_t)N * 4, stream);

    gemm_relu_kernel<<<dim3((N + BM - 1) / BM), dim3(256), 0, stream>>>(h, W, b, hr, N);
    scatter_kernel<<<dim3((E + 3) / 4), dim3(256), 0, stream>>>(hr, src, dst, out, deg, E);
    finalize_kernel<<<dim3((N * 32 + 255) / 256), dim3(256), 0, stream>>>(hr, deg, out, N);
}

// Round 4
// 420.846 us; speedup vs baseline: 3.6513x; 3.6513x over previous
//
#include <hip/hip_runtime.h>
#include <hip/hip_bf16.h>

// a_mean_op: out = where(deg>0, segment_mean(relu(h @ W.T + b)[src], dst), hr)
// R4: kill the fp32 atomic scatter (was 1.36 ms, atomic-RMW-bound: WRITE_SIZE
//     1.65 GB = 205M x 8B). Build CSR in-kernel (int atomics only), then
//     wave-per-node GATHER from L3-resident bf16 hr, fp32 register accumulate,
//     single write of out. No out memset needed.

#define FEAT 128

using bf16 = __hip_bfloat16;
typedef __attribute__((ext_vector_type(8))) short short8_;   // 8 x bf16
typedef __attribute__((ext_vector_type(4))) short bhalf4;    // 4 x bf16
typedef __attribute__((ext_vector_type(4))) float floatx4;

// ---------------------------------------------------------------------------
// Kernel 1: hr = bf16(relu(h @ W.T + b)). (unchanged from R3)
// ---------------------------------------------------------------------------
#define BM 64
__launch_bounds__(256)
__global__ void gemm_relu_kernel(const float* __restrict__ h,
                                 const float* __restrict__ W,
                                 const float* __restrict__ b,
                                 bf16* __restrict__ hr, int M) {
    __shared__ bf16 sA[BM][136];
    __shared__ bf16 sW[FEAT][136];

    const int tid  = threadIdx.x;
    const int row0 = blockIdx.x * BM;

    #pragma unroll
    for (int i = 0; i < 16; ++i) {
        int v = i * 256 + tid;
        int r = v >> 5;
        int c = (v & 31) * 4;
        float4 f = *(const float4*)(W + (size_t)r * FEAT + c);
        bhalf4 s;
        s[0] = __bfloat16_as_short(__float2bfloat16(f.x));
        s[1] = __bfloat16_as_short(__float2bfloat16(f.y));
        s[2] = __bfloat16_as_short(__float2bfloat16(f.z));
        s[3] = __bfloat16_as_short(__float2bfloat16(f.w));
        *(bhalf4*)(&sW[r][c]) = s;
    }
    #pragma unroll
    for (int i = 0; i < 8; ++i) {
        int v = i * 256 + tid;
        int r = v >> 5;
        int c = (v & 31) * 4;
        int row = row0 + r;
        float4 f = make_float4(0.f, 0.f, 0.f, 0.f);
        if (row < M) f = *(const float4*)(h + (size_t)row * FEAT + c);
        bhalf4 s;
        s[0] = __bfloat16_as_short(__float2bfloat16(f.x));
        s[1] = __bfloat16_as_short(__float2bfloat16(f.y));
        s[2] = __bfloat16_as_short(__float2bfloat16(f.z));
        s[3] = __bfloat16_as_short(__float2bfloat16(f.w));
        *(bhalf4*)(&sA[r][c]) = s;
    }
    __syncthreads();

    const int wave = tid >> 6;
    const int lane = tid & 63;
    const int m    = lane & 15;
    const int ko   = (lane >> 4) * 8;

    floatx4 acc[8];
    #pragma unroll
    for (int t = 0; t < 8; ++t) acc[t] = floatx4{0.f, 0.f, 0.f, 0.f};

    #pragma unroll
    for (int k0 = 0; k0 < FEAT; k0 += 32) {
        short8_ afrag = *(const short8_*)(&sA[wave * 16 + m][k0 + ko]);
        #pragma unroll
        for (int nt = 0; nt < 8; ++nt) {
            short8_ bfrag = *(const short8_*)(&sW[nt * 16 + m][k0 + ko]);
            acc[nt] = __builtin_amdgcn_mfma_f32_16x16x32_bf16(afrag, bfrag, acc[nt], 0, 0, 0);
        }
    }

    const int rbase = row0 + wave * 16 + (lane >> 4) * 4;
    #pragma unroll
    for (int nt = 0; nt < 8; ++nt) {
        int col = nt * 16 + m;
        float bias = b[col];
        #pragma unroll
        for (int r = 0; r < 4; ++r) {
            int row = rbase + r;
            if (row < M) {
                float v = fmaxf(acc[nt][r] + bias, 0.0f);
                hr[(size_t)row * FEAT + col] = __float2bfloat16(v);
            }
        }
    }
}

// ---------------------------------------------------------------------------
// CSR build. Kernel 2: degree histogram (int atomics).
// ---------------------------------------------------------------------------
__launch_bounds__(256)
__global__ void hist_kernel(const int* __restrict__ dst, int* __restrict__ deg, int E) {
    int e = blockIdx.x * 256 + threadIdx.x;
    if (e < E) atomicAdd(&deg[dst[e]], 1);
}

// Kernel 3a: per-block (1024-element) partial sums of deg.
__launch_bounds__(256)
__global__ void scan_partial_kernel(const int* __restrict__ deg, int* __restrict__ bsum, int N) {
    __shared__ int sdata[256];
    int base = blockIdx.x * 1024;
    int t = threadIdx.x;
    int s = 0;
    #pragma unroll
    for (int i = 0; i < 4; ++i) {
        int idx = base + t * 4 + i;
        if (idx < N) s += deg[idx];
    }
    sdata[t] = s;
    __syncthreads();
    for (int off = 128; off > 0; off >>= 1) {
        if (t < off) sdata[t] += sdata[t + off];
        __syncthreads();
    }
    if (t == 0) bsum[blockIdx.x] = sdata[0];
}

// Kernel 3b: serial exclusive scan of block sums (~100 elements).
__global__ void scan_bsums_kernel(int* __restrict__ bsum, int nb) {
    if (threadIdx.x == 0 && blockIdx.x == 0) {
        int run = 0;
        for (int i = 0; i < nb; ++i) {
            int v = bsum[i];
            bsum[i] = run;
            run += v;
        }
    }
}

// Kernel 3c: per-block exclusive scan + block offset -> rowptr.
__launch_bounds__(256)
__global__ void scan_final_kernel(const int* __restrict__ deg, const int* __restrict__ bsum,
                                  int* __restrict__ rowptr, int N, int E) {
    __shared__ int sdata[256];
    int base = blockIdx.x * 1024;
    int t = threadIdx.x;
    int v[4];
    int s = 0;
    #pragma unroll
    for (int i = 0; i < 4; ++i) {
        int idx = base + t * 4 + i;
        v[i] = (idx < N) ? deg[idx] : 0;
        s += v[i];
    }
    sdata[t] = s;
    __syncthreads();
    // Hillis-Steele inclusive scan over thread sums
    for (int off = 1; off < 256; off <<= 1) {
        int y = (t >= off) ? sdata[t - off] : 0;
        __syncthreads();
        sdata[t] += y;
        __syncthreads();
    }
    int excl = sdata[t] - s + bsum[blockIdx.x];
    #pragma unroll
    for (int i = 0; i < 4; ++i) {
        int idx = base + t * 4 + i;
        if (idx < N) rowptr[idx] = excl;
        excl += v[i];
    }
    if (blockIdx.x == 0 && t == 0) rowptr[N] = E;
}

// Kernel 4: fill edge slots. atomicSub on deg reuses it as a cursor
// (order within a segment is irrelevant for a sum). deg ends at 0.
__launch_bounds__(256)
__global__ void fill_kernel(const int* __restrict__ src, const int* __restrict__ dst,
                            const int* __restrict__ rowptr, int* __restrict__ deg,
                            int* __restrict__ eidx, int E) {
    int e = blockIdx.x * 256 + threadIdx.x;
    if (e >= E) return;
    int d = dst[e];
    int old = atomicSub(&deg[d], 1);           // old in [1..degree]
    eidx[rowptr[d] + old - 1] = src[e];
}

// ---------------------------------------------------------------------------
// Kernel 5: gather. One wave per node; lane owns feats {2*lane, 2*lane+1}.
// fp32 register accumulation, single coalesced out write. 2-deep unroll for ILP.
// ---------------------------------------------------------------------------
__launch_bounds__(256)
__global__ void gather_kernel(const bf16* __restrict__ hr,
                              const int* __restrict__ rowptr,
                              const int* __restrict__ eidx,
                              float* __restrict__ out, int N) {
    int node = blockIdx.x * 4 + (threadIdx.x >> 6);
    if (node >= N) return;
    int lane = threadIdx.x & 63;
    int beg = rowptr[node];
    int end = rowptr[node + 1];

    const __hip_bfloat162* hp = (const __hip_bfloat162*)hr;   // 64 pairs per row
    float2 acc0 = make_float2(0.f, 0.f);
    float2 acc1 = make_float2(0.f, 0.f);

    int e = beg;
    for (; e + 1 < end; e += 2) {
        int s0 = eidx[e];
        int s1 = eidx[e + 1];
        float2 f0 = __bfloat1622float2(hp[(size_t)s0 * 64 + lane]);
        float2 f1 = __bfloat1622float2(hp[(size_t)s1 * 64 + lane]);
        acc0.x += f0.x; acc0.y += f0.y;
        acc1.x += f1.x; acc1.y += f1.y;
    }
    if (e < end) {
        int s0 = eidx[e];
        float2 f0 = __bfloat1622float2(hp[(size_t)s0 * 64 + lane]);
        acc0.x += f0.x; acc0.y += f0.y;
    }

    int d = end - beg;
    float2 r;
    if (d > 0) {
        float inv = 1.0f / (float)d;
        r.x = (acc0.x + acc1.x) * inv;
        r.y = (acc0.y + acc1.y) * inv;
    } else {
        r = __bfloat1622float2(hp[(size_t)node * 64 + lane]);
    }
    *(float2*)(out + (size_t)node * FEAT + lane * 2) = r;
}

// ---------------------------------------------------------------------------
extern "C" void kernel_launch(void* const* d_in, const int* in_sizes, int n_in,
                              void* d_out, int out_size, void* d_ws, size_t ws_size,
                              hipStream_t stream) {
    const float* h   = (const float*)d_in[0];
    const int*   src = (const int*)d_in[2];
    const int*   dst = (const int*)d_in[3];
    const float* W   = (const float*)d_in[4];
    const float* b   = (const float*)d_in[5];
    float* out = (float*)d_out;

    const int N = in_sizes[0] / FEAT;
    const int E = in_sizes[2];
    const int NB = (N + 1023) / 1024;   // scan blocks

    // ws layout: hr bf16[N*128] | rowptr int[N+1] | deg int[N] | eidx int[E] | bsum int[NB]
    char* ws = (char*)d_ws;
    size_t off = 0;
    bf16* hr     = (bf16*)(ws + off); off += (size_t)N * FEAT * 2;
    int*  rowptr = (int*)(ws + off);  off += (size_t)(N + 1) * 4;
    int*  deg    = (int*)(ws + off);  off += (size_t)N * 4;
    int*  eidx   = (int*)(ws + off);  off += (size_t)E * 4;
    int*  bsum   = (int*)(ws + off);  off += (size_t)NB * 4;

    (void)hipMemsetAsync(deg, 0, (size_t)N * 4, stream);

    gemm_relu_kernel<<<dim3((N + BM - 1) / BM), dim3(256), 0, stream>>>(h, W, b, hr, N);
    hist_kernel<<<dim3((E + 255) / 256), dim3(256), 0, stream>>>(dst, deg, E);
    scan_partial_kernel<<<dim3(NB), dim3(256), 0, stream>>>(deg, bsum, N);
    scan_bsums_kernel<<<dim3(1), dim3(64), 0, stream>>>(bsum, NB);
    scan_final_kernel<<<dim3(NB), dim3(256), 0, stream>>>(deg, bsum, rowptr, N, E);
    fill_kernel<<<dim3((E + 255) / 256), dim3(256), 0, stream>>>(src, dst, rowptr, deg, eidx, E);
    gather_kernel<<<dim3((N + 3) / 4), dim3(256), 0, stream>>>(hr, rowptr, eidx, out, N);
}

// Round 5
// 405.667 us; speedup vs baseline: 3.7879x; 1.0374x over previous
//
#include <hip/hip_runtime.h>
#include <hip/hip_bf16.h>

// a_mean_op: out = where(deg>0, segment_mean(relu(h @ W.T + b)[src], dst), hr)
// R5: (1) pre-convert h,W -> bf16 once, fused with degree histogram (independent
//     chains overlap in one grid); (2) GEMM stages pure bf16, fused with
//     scan_partial; (3) wave-parallel block-sum scan; (4) gather 4-deep unroll.

#define FEAT 128

using bf16 = __hip_bfloat16;
typedef __attribute__((ext_vector_type(8))) short short8_;   // 8 x bf16
typedef __attribute__((ext_vector_type(4))) short bhalf4;    // 4 x bf16
typedef __attribute__((ext_vector_type(4))) float floatx4;

__device__ __forceinline__ bhalf4 cvt4(float4 f) {
    bhalf4 s;
    s[0] = __bfloat16_as_short(__float2bfloat16(f.x));
    s[1] = __bfloat16_as_short(__float2bfloat16(f.y));
    s[2] = __bfloat16_as_short(__float2bfloat16(f.z));
    s[3] = __bfloat16_as_short(__float2bfloat16(f.w));
    return s;
}

// ---------------------------------------------------------------------------
// K0: fused  [h fp32->bf16] + [W fp32->bf16] + [deg histogram]
// grid = CB_H + CB_W + CB_E blocks, branch on block range (no divergence
// within a block). Conversion is BW-bound; hist is atomic/latency-bound —
// they overlap instead of serializing.
// ---------------------------------------------------------------------------
__launch_bounds__(256)
__global__ void convert_hist_kernel(const float* __restrict__ h, bf16* __restrict__ hb,
                                    const float* __restrict__ W, bf16* __restrict__ Wb,
                                    const int* __restrict__ dst, int* __restrict__ deg,
                                    int nh4, int nw4, int E, int cbh, int cbw) {
    int bid = blockIdx.x;
    if (bid < cbh) {
        // h convert: 4 float4 per thread
        int base = (bid * 256 + threadIdx.x) * 4;
        #pragma unroll
        for (int i = 0; i < 4; ++i) {
            int v = base + i;
            if (v < nh4) ((bhalf4*)hb)[v] = cvt4(((const float4*)h)[v]);
        }
    } else if (bid < cbh + cbw) {
        int base = ((bid - cbh) * 256 + threadIdx.x) * 4;
        #pragma unroll
        for (int i = 0; i < 4; ++i) {
            int v = base + i;
            if (v < nw4) ((bhalf4*)Wb)[v] = cvt4(((const float4*)W)[v]);
        }
    } else {
        int base = ((bid - cbh - cbw) * 256 + threadIdx.x) * 4;
        #pragma unroll
        for (int i = 0; i < 4; ++i) {
            int e = base + i;
            if (e < E) atomicAdd(&deg[dst[e]], 1);
        }
    }
}

// ---------------------------------------------------------------------------
// K1: fused  [bf16 GEMM hr = relu(hb @ Wb^T + b)] + [scan_partial over deg]
// GEMM: BM=64 rows/block, 4 waves, 16x16x32 MFMA, m92-verified frag layout.
// ---------------------------------------------------------------------------
#define BM 64
__launch_bounds__(256)
__global__ void gemm_scanp_kernel(const bf16* __restrict__ hb, const bf16* __restrict__ Wb,
                                  const float* __restrict__ b, bf16* __restrict__ hr, int M,
                                  const int* __restrict__ deg, int* __restrict__ bsum,
                                  int N, int gb) {
    __shared__ bf16 sA[BM][136];
    __shared__ bf16 sW[FEAT][136];
    __shared__ int sdata[256];

    if (blockIdx.x >= gb) {
        // ---- scan_partial: 1024 deg entries per block -> bsum ----
        int base = (blockIdx.x - gb) * 1024;
        int t = threadIdx.x;
        int s = 0;
        #pragma unroll
        for (int i = 0; i < 4; ++i) {
            int idx = base + t * 4 + i;
            if (idx < N) s += deg[idx];
        }
        sdata[t] = s;
        __syncthreads();
        for (int off = 128; off > 0; off >>= 1) {
            if (t < off) sdata[t] += sdata[t + off];
            __syncthreads();
        }
        if (t == 0) bsum[blockIdx.x - gb] = sdata[0];
        return;
    }

    const int tid  = threadIdx.x;
    const int row0 = blockIdx.x * BM;

    // stage Wb: 2048 short8_ (16B), 8 per thread
    #pragma unroll
    for (int i = 0; i < 8; ++i) {
        int v = i * 256 + tid;
        int r = v >> 4;                 // 16 vecs/row
        int c = (v & 15) * 8;
        *(short8_*)(&sW[r][c]) = *(const short8_*)(Wb + (size_t)r * FEAT + c);
    }
    // stage A: 1024 short8_, 4 per thread
    #pragma unroll
    for (int i = 0; i < 4; ++i) {
        int v = i * 256 + tid;
        int r = v >> 4;
        int c = (v & 15) * 8;
        int row = row0 + r;
        short8_ val = short8_{0,0,0,0,0,0,0,0};
        if (row < M) val = *(const short8_*)(hb + (size_t)row * FEAT + c);
        *(short8_*)(&sA[r][c]) = val;
    }
    __syncthreads();

    const int wave = tid >> 6;
    const int lane = tid & 63;
    const int m    = lane & 15;
    const int ko   = (lane >> 4) * 8;

    floatx4 acc[8];
    #pragma unroll
    for (int t = 0; t < 8; ++t) acc[t] = floatx4{0.f, 0.f, 0.f, 0.f};

    #pragma unroll
    for (int k0 = 0; k0 < FEAT; k0 += 32) {
        short8_ afrag = *(const short8_*)(&sA[wave * 16 + m][k0 + ko]);
        #pragma unroll
        for (int nt = 0; nt < 8; ++nt) {
            short8_ bfrag = *(const short8_*)(&sW[nt * 16 + m][k0 + ko]);
            acc[nt] = __builtin_amdgcn_mfma_f32_16x16x32_bf16(afrag, bfrag, acc[nt], 0, 0, 0);
        }
    }

    const int rbase = row0 + wave * 16 + (lane >> 4) * 4;
    #pragma unroll
    for (int nt = 0; nt < 8; ++nt) {
        int col = nt * 16 + m;
        float bias = b[col];
        #pragma unroll
        for (int r = 0; r < 4; ++r) {
            int row = rbase + r;
            if (row < M) {
                float v = fmaxf(acc[nt][r] + bias, 0.0f);
                hr[(size_t)row * FEAT + col] = __float2bfloat16(v);
            }
        }
    }
}

// ---------------------------------------------------------------------------
// K2: exclusive scan of block sums (NB <= 256), one block, LDS Hillis-Steele.
// ---------------------------------------------------------------------------
__launch_bounds__(256)
__global__ void scan_bsums_kernel(int* __restrict__ bsum, int nb) {
    __shared__ int sdata[256];
    int t = threadIdx.x;
    int v = (t < nb) ? bsum[t] : 0;
    sdata[t] = v;
    __syncthreads();
    for (int off = 1; off < 256; off <<= 1) {
        int y = (t >= off) ? sdata[t - off] : 0;
        __syncthreads();
        sdata[t] += y;
        __syncthreads();
    }
    if (t < nb) bsum[t] = sdata[t] - v;   // exclusive
}

// ---------------------------------------------------------------------------
// K3: per-block exclusive scan + offset -> rowptr
// ---------------------------------------------------------------------------
__launch_bounds__(256)
__global__ void scan_final_kernel(const int* __restrict__ deg, const int* __restrict__ bsum,
                                  int* __restrict__ rowptr, int N, int E) {
    __shared__ int sdata[256];
    int base = blockIdx.x * 1024;
    int t = threadIdx.x;
    int v[4];
    int s = 0;
    #pragma unroll
    for (int i = 0; i < 4; ++i) {
        int idx = base + t * 4 + i;
        v[i] = (idx < N) ? deg[idx] : 0;
        s += v[i];
    }
    sdata[t] = s;
    __syncthreads();
    for (int off = 1; off < 256; off <<= 1) {
        int y = (t >= off) ? sdata[t - off] : 0;
        __syncthreads();
        sdata[t] += y;
        __syncthreads();
    }
    int excl = sdata[t] - s + bsum[blockIdx.x];
    #pragma unroll
    for (int i = 0; i < 4; ++i) {
        int idx = base + t * 4 + i;
        if (idx < N) rowptr[idx] = excl;
        excl += v[i];
    }
    if (blockIdx.x == 0 && t == 0) rowptr[N] = E;
}

// ---------------------------------------------------------------------------
// K4: fill edge slots (atomicSub on deg as cursor; deg ends at 0).
// ---------------------------------------------------------------------------
__launch_bounds__(256)
__global__ void fill_kernel(const int* __restrict__ src, const int* __restrict__ dst,
                            const int* __restrict__ rowptr, int* __restrict__ deg,
                            int* __restrict__ eidx, int E) {
    int e = blockIdx.x * 256 + threadIdx.x;
    if (e >= E) return;
    int d = dst[e];
    int old = atomicSub(&deg[d], 1);
    eidx[rowptr[d] + old - 1] = src[e];
}

// ---------------------------------------------------------------------------
// K5: gather. One wave/node, lane owns feats {2L, 2L+1}; 4-deep unroll for MLP.
// ---------------------------------------------------------------------------
__launch_bounds__(256)
__global__ void gather_kernel(const bf16* __restrict__ hr,
                              const int* __restrict__ rowptr,
                              const int* __restrict__ eidx,
                              float* __restrict__ out, int N) {
    int node = blockIdx.x * 4 + (threadIdx.x >> 6);
    if (node >= N) return;
    int lane = threadIdx.x & 63;
    int beg = rowptr[node];
    int end = rowptr[node + 1];

    const __hip_bfloat162* hp = (const __hip_bfloat162*)hr;   // 64 pairs/row
    float2 a0 = make_float2(0.f, 0.f), a1 = make_float2(0.f, 0.f);
    float2 a2 = make_float2(0.f, 0.f), a3 = make_float2(0.f, 0.f);

    int e = beg;
    for (; e + 3 < end; e += 4) {
        int s0 = eidx[e], s1 = eidx[e + 1], s2 = eidx[e + 2], s3 = eidx[e + 3];
        float2 f0 = __bfloat1622float2(hp[(size_t)s0 * 64 + lane]);
        float2 f1 = __bfloat1622float2(hp[(size_t)s1 * 64 + lane]);
        float2 f2 = __bfloat1622float2(hp[(size_t)s2 * 64 + lane]);
        float2 f3 = __bfloat1622float2(hp[(size_t)s3 * 64 + lane]);
        a0.x += f0.x; a0.y += f0.y;
        a1.x += f1.x; a1.y += f1.y;
        a2.x += f2.x; a2.y += f2.y;
        a3.x += f3.x; a3.y += f3.y;
    }
    for (; e < end; ++e) {
        int s0 = eidx[e];
        float2 f0 = __bfloat1622float2(hp[(size_t)s0 * 64 + lane]);
        a0.x += f0.x; a0.y += f0.y;
    }

    int d = end - beg;
    float2 r;
    if (d > 0) {
        float inv = 1.0f / (float)d;
        r.x = (a0.x + a1.x + a2.x + a3.x) * inv;
        r.y = (a0.y + a1.y + a2.y + a3.y) * inv;
    } else {
        r = __bfloat1622float2(hp[(size_t)node * 64 + lane]);
    }
    *(float2*)(out + (size_t)node * FEAT + lane * 2) = r;
}

// ---------------------------------------------------------------------------
extern "C" void kernel_launch(void* const* d_in, const int* in_sizes, int n_in,
                              void* d_out, int out_size, void* d_ws, size_t ws_size,
                              hipStream_t stream) {
    const float* h   = (const float*)d_in[0];
    const int*   src = (const int*)d_in[2];
    const int*   dst = (const int*)d_in[3];
    const float* W   = (const float*)d_in[4];
    const float* b   = (const float*)d_in[5];
    float* out = (float*)d_out;

    const int N = in_sizes[0] / FEAT;
    const int E = in_sizes[2];
    const int NB = (N + 1023) / 1024;            // scan blocks (98 for N=100k)

    // ws layout: hb bf16[N*128] | hr bf16[N*128] | Wb bf16[128*128]
    //          | rowptr int[N+1] | deg int[N] | eidx int[E] | bsum int[NB]
    char* ws = (char*)d_ws;
    size_t off = 0;
    bf16* hb     = (bf16*)(ws + off); off += (size_t)N * FEAT * 2;
    bf16* hr     = (bf16*)(ws + off); off += (size_t)N * FEAT * 2;
    bf16* Wb     = (bf16*)(ws + off); off += (size_t)FEAT * FEAT * 2;
    int*  rowptr = (int*)(ws + off);  off += (size_t)(N + 1) * 4;
    int*  deg    = (int*)(ws + off);  off += (size_t)N * 4;
    int*  eidx   = (int*)(ws + off);  off += (size_t)E * 4;
    int*  bsum   = (int*)(ws + off);  off += (size_t)NB * 4;

    (void)hipMemsetAsync(deg, 0, (size_t)N * 4, stream);

    const int nh4 = N * FEAT / 4;                // float4 count of h
    const int nw4 = FEAT * FEAT / 4;
    const int cbh = (nh4 + 1023) / 1024;         // 4 float4/thread
    const int cbw = (nw4 + 1023) / 1024;
    const int cbe = (E + 1023) / 1024;
    convert_hist_kernel<<<dim3(cbh + cbw + cbe), dim3(256), 0, stream>>>(
        h, hb, W, Wb, dst, deg, nh4, nw4, E, cbh, cbw);

    const int gb = (N + BM - 1) / BM;
    gemm_scanp_kernel<<<dim3(gb + NB), dim3(256), 0, stream>>>(
        hb, Wb, b, hr, N, deg, bsum, N, gb);

    scan_bsums_kernel<<<dim3(1), dim3(256), 0, stream>>>(bsum, NB);
    scan_final_kernel<<<dim3(NB), dim3(256), 0, stream>>>(deg, bsum, rowptr, N, E);
    fill_kernel<<<dim3((E + 255) / 256), dim3(256), 0, stream>>>(src, dst, rowptr, deg, eidx, E);
    gather_kernel<<<dim3((N + 3) / 4), dim3(256), 0, stream>>>(hr, rowptr, eidx, out, N);
}

// Round 6
// 376.311 us; speedup vs baseline: 4.0834x; 1.0780x over previous
//
#include <hip/hip_runtime.h>
#include <hip/hip_bf16.h>

// a_mean_op: out = where(deg>0, segment_mean(relu(h @ W.T + b)[src], dst), hr)
// R6: drop the h pre-convert pass (was 96us, DRAM-thrashing mix of stream+atomics;
//     GEMM converts during staging instead, h read exactly once). W converted once
//     in the hist kernel. Gather: 2 edges/wave via 8B loads, 8 edges in flight,
//     cross-half shfl_xor combine.

#define FEAT 128

using bf16 = __hip_bfloat16;
typedef __attribute__((ext_vector_type(8))) short short8_;   // 8 x bf16
typedef __attribute__((ext_vector_type(4))) short bhalf4;    // 4 x bf16
typedef __attribute__((ext_vector_type(4))) float floatx4;

__device__ __forceinline__ bhalf4 cvt4(float4 f) {
    bhalf4 s;
    s[0] = __bfloat16_as_short(__float2bfloat16(f.x));
    s[1] = __bfloat16_as_short(__float2bfloat16(f.y));
    s[2] = __bfloat16_as_short(__float2bfloat16(f.z));
    s[3] = __bfloat16_as_short(__float2bfloat16(f.w));
    return s;
}
__device__ __forceinline__ float4 b2f4(bhalf4 s) {
    float4 f;
    f.x = __bfloat162float(__short_as_bfloat16(s[0]));
    f.y = __bfloat162float(__short_as_bfloat16(s[1]));
    f.z = __bfloat162float(__short_as_bfloat16(s[2]));
    f.w = __bfloat162float(__short_as_bfloat16(s[3]));
    return f;
}

// ---------------------------------------------------------------------------
// K0: [deg histogram over dst] + [W fp32->bf16, 4 blocks]
// ---------------------------------------------------------------------------
__launch_bounds__(256)
__global__ void hist_wcvt_kernel(const int* __restrict__ dst, int* __restrict__ deg, int E,
                                 const float* __restrict__ W, bf16* __restrict__ Wb,
                                 int cbe) {
    int bid = blockIdx.x;
    if (bid < cbe) {
        int base = (bid * 256 + threadIdx.x) * 4;
        #pragma unroll
        for (int i = 0; i < 4; ++i) {
            int e = base + i;
            if (e < E) atomicAdd(&deg[dst[e]], 1);
        }
    } else {
        // W: 128*128 = 4096 float4 over 4 blocks
        int base = ((bid - cbe) * 256 + threadIdx.x) * 4;
        #pragma unroll
        for (int i = 0; i < 4; ++i) {
            int v = base + i;
            ((bhalf4*)Wb)[v] = cvt4(((const float4*)W)[v]);
        }
    }
}

// ---------------------------------------------------------------------------
// K1: fused [GEMM hr = bf16(relu(h @ Wb^T + b))] + [scan_partial over deg].
// A staged fp32->bf16 in-kernel (h read exactly once across the grid).
// ---------------------------------------------------------------------------
#define BM 64
__launch_bounds__(256)
__global__ void gemm_scanp_kernel(const float* __restrict__ h, const bf16* __restrict__ Wb,
                                  const float* __restrict__ b, bf16* __restrict__ hr, int M,
                                  const int* __restrict__ deg, int* __restrict__ bsum,
                                  int N, int gb) {
    __shared__ bf16 sA[BM][136];
    __shared__ bf16 sW[FEAT][136];
    __shared__ int sdata[256];

    if (blockIdx.x >= gb) {
        // ---- scan_partial: 1024 deg entries -> bsum ----
        int base = (blockIdx.x - gb) * 1024;
        int t = threadIdx.x;
        int s = 0;
        #pragma unroll
        for (int i = 0; i < 4; ++i) {
            int idx = base + t * 4 + i;
            if (idx < N) s += deg[idx];
        }
        sdata[t] = s;
        __syncthreads();
        for (int off = 128; off > 0; off >>= 1) {
            if (t < off) sdata[t] += sdata[t + off];
            __syncthreads();
        }
        if (t == 0) bsum[blockIdx.x - gb] = sdata[0];
        return;
    }

    const int tid  = threadIdx.x;
    const int row0 = blockIdx.x * BM;

    // stage Wb (bf16): 2048 short8_, 8 per thread
    #pragma unroll
    for (int i = 0; i < 8; ++i) {
        int v = i * 256 + tid;
        int r = v >> 4;
        int c = (v & 15) * 8;
        *(short8_*)(&sW[r][c]) = *(const short8_*)(Wb + (size_t)r * FEAT + c);
    }
    // stage A (fp32 -> bf16): 2048 float4, 8 per thread
    #pragma unroll
    for (int i = 0; i < 8; ++i) {
        int v = i * 256 + tid;
        int r = v >> 5;                 // 32 float4 per row
        int c = (v & 31) * 4;
        int row = row0 + r;
        float4 f = make_float4(0.f, 0.f, 0.f, 0.f);
        if (row < M) f = *(const float4*)(h + (size_t)row * FEAT + c);
        *(bhalf4*)(&sA[r][c]) = cvt4(f);
    }
    __syncthreads();

    const int wave = tid >> 6;
    const int lane = tid & 63;
    const int m    = lane & 15;
    const int ko   = (lane >> 4) * 8;

    floatx4 acc[8];
    #pragma unroll
    for (int t = 0; t < 8; ++t) acc[t] = floatx4{0.f, 0.f, 0.f, 0.f};

    #pragma unroll
    for (int k0 = 0; k0 < FEAT; k0 += 32) {
        short8_ afrag = *(const short8_*)(&sA[wave * 16 + m][k0 + ko]);
        #pragma unroll
        for (int nt = 0; nt < 8; ++nt) {
            short8_ bfrag = *(const short8_*)(&sW[nt * 16 + m][k0 + ko]);
            acc[nt] = __builtin_amdgcn_mfma_f32_16x16x32_bf16(afrag, bfrag, acc[nt], 0, 0, 0);
        }
    }

    const int rbase = row0 + wave * 16 + (lane >> 4) * 4;
    #pragma unroll
    for (int nt = 0; nt < 8; ++nt) {
        int col = nt * 16 + m;
        float bias = b[col];
        #pragma unroll
        for (int r = 0; r < 4; ++r) {
            int row = rbase + r;
            if (row < M) {
                float v = fmaxf(acc[nt][r] + bias, 0.0f);
                hr[(size_t)row * FEAT + col] = __float2bfloat16(v);
            }
        }
    }
}

// ---------------------------------------------------------------------------
// K2: exclusive scan of block sums (NB <= 256), one block.
// ---------------------------------------------------------------------------
__launch_bounds__(256)
__global__ void scan_bsums_kernel(int* __restrict__ bsum, int nb) {
    __shared__ int sdata[256];
    int t = threadIdx.x;
    int v = (t < nb) ? bsum[t] : 0;
    sdata[t] = v;
    __syncthreads();
    for (int off = 1; off < 256; off <<= 1) {
        int y = (t >= off) ? sdata[t - off] : 0;
        __syncthreads();
        sdata[t] += y;
        __syncthreads();
    }
    if (t < nb) bsum[t] = sdata[t] - v;
}

// ---------------------------------------------------------------------------
// K3: per-block exclusive scan + offset -> rowptr
// ---------------------------------------------------------------------------
__launch_bounds__(256)
__global__ void scan_final_kernel(const int* __restrict__ deg, const int* __restrict__ bsum,
                                  int* __restrict__ rowptr, int N, int E) {
    __shared__ int sdata[256];
    int base = blockIdx.x * 1024;
    int t = threadIdx.x;
    int v[4];
    int s = 0;
    #pragma unroll
    for (int i = 0; i < 4; ++i) {
        int idx = base + t * 4 + i;
        v[i] = (idx < N) ? deg[idx] : 0;
        s += v[i];
    }
    sdata[t] = s;
    __syncthreads();
    for (int off = 1; off < 256; off <<= 1) {
        int y = (t >= off) ? sdata[t - off] : 0;
        __syncthreads();
        sdata[t] += y;
        __syncthreads();
    }
    int excl = sdata[t] - s + bsum[blockIdx.x];
    #pragma unroll
    for (int i = 0; i < 4; ++i) {
        int idx = base + t * 4 + i;
        if (idx < N) rowptr[idx] = excl;
        excl += v[i];
    }
    if (blockIdx.x == 0 && t == 0) rowptr[N] = E;
}

// ---------------------------------------------------------------------------
// K4: fill edge slots (atomicSub on deg as cursor; deg ends at 0).
// ---------------------------------------------------------------------------
__launch_bounds__(256)
__global__ void fill_kernel(const int* __restrict__ src, const int* __restrict__ dst,
                            const int* __restrict__ rowptr, int* __restrict__ deg,
                            int* __restrict__ eidx, int E) {
    int e = blockIdx.x * 256 + threadIdx.x;
    if (e >= E) return;
    int d = dst[e];
    int old = atomicSub(&deg[d], 1);
    eidx[rowptr[d] + old - 1] = src[e];
}

// ---------------------------------------------------------------------------
// K5: gather. One wave per node; half-wave (32 lanes) per edge, 8B bhalf4
// loads (lane&31 covers the 256B row), 4 pair-iters unrolled = 8 edges in
// flight. Cross-half combine via shfl_xor(32) at the end.
// ---------------------------------------------------------------------------
__launch_bounds__(256)
__global__ void gather_kernel(const bf16* __restrict__ hr,
                              const int* __restrict__ rowptr,
                              const int* __restrict__ eidx,
                              float* __restrict__ out, int N) {
    int node = blockIdx.x * 4 + (threadIdx.x >> 6);
    if (node >= N) return;
    int lane = threadIdx.x & 63;
    int half = lane >> 5;          // which edge of the pair
    int l32  = lane & 31;          // bhalf4 index within a 256B row

    int beg = rowptr[node];
    int end = rowptr[node + 1];

    const bhalf4* hp4 = (const bhalf4*)hr;   // 32 per row
    float4 a0 = make_float4(0.f,0.f,0.f,0.f), a1 = make_float4(0.f,0.f,0.f,0.f);
    float4 a2 = make_float4(0.f,0.f,0.f,0.f), a3 = make_float4(0.f,0.f,0.f,0.f);

    int e = beg;
    for (; e + 7 < end; e += 8) {
        int s0 = eidx[e + 0 + half];
        int s1 = eidx[e + 2 + half];
        int s2 = eidx[e + 4 + half];
        int s3 = eidx[e + 6 + half];
        float4 f0 = b2f4(hp4[(size_t)s0 * 32 + l32]);
        float4 f1 = b2f4(hp4[(size_t)s1 * 32 + l32]);
        float4 f2 = b2f4(hp4[(size_t)s2 * 32 + l32]);
        float4 f3 = b2f4(hp4[(size_t)s3 * 32 + l32]);
        a0.x += f0.x; a0.y += f0.y; a0.z += f0.z; a0.w += f0.w;
        a1.x += f1.x; a1.y += f1.y; a1.z += f1.z; a1.w += f1.w;
        a2.x += f2.x; a2.y += f2.y; a2.z += f2.z; a2.w += f2.w;
        a3.x += f3.x; a3.y += f3.y; a3.z += f3.z; a3.w += f3.w;
    }
    for (; e < end; e += 2) {
        int ei = e + half;
        if (ei < end) {
            int s0 = eidx[ei];
            float4 f0 = b2f4(hp4[(size_t)s0 * 32 + l32]);
            a0.x += f0.x; a0.y += f0.y; a0.z += f0.z; a0.w += f0.w;
        }
    }

    a0.x += a1.x + a2.x + a3.x;
    a0.y += a1.y + a2.y + a3.y;
    a0.z += a1.z + a2.z + a3.z;
    a0.w += a1.w + a2.w + a3.w;
    // combine the two halves (other half holds the other edges' partial sums)
    a0.x += __shfl_xor(a0.x, 32, 64);
    a0.y += __shfl_xor(a0.y, 32, 64);
    a0.z += __shfl_xor(a0.z, 32, 64);
    a0.w += __shfl_xor(a0.w, 32, 64);

    int d = end - beg;
    float4 r;
    if (d > 0) {
        float inv = 1.0f / (float)d;
        r.x = a0.x * inv; r.y = a0.y * inv; r.z = a0.z * inv; r.w = a0.w * inv;
    } else {
        r = b2f4(hp4[(size_t)node * 32 + l32]);
    }
    if (half == 0)
        *(float4*)(out + (size_t)node * FEAT + l32 * 4) = r;
}

// ---------------------------------------------------------------------------
extern "C" void kernel_launch(void* const* d_in, const int* in_sizes, int n_in,
                              void* d_out, int out_size, void* d_ws, size_t ws_size,
                              hipStream_t stream) {
    const float* h   = (const float*)d_in[0];
    const int*   src = (const int*)d_in[2];
    const int*   dst = (const int*)d_in[3];
    const float* W   = (const float*)d_in[4];
    const float* b   = (const float*)d_in[5];
    float* out = (float*)d_out;

    const int N = in_sizes[0] / FEAT;
    const int E = in_sizes[2];
    const int NB = (N + 1023) / 1024;

    // ws: hr bf16[N*128] | Wb bf16[128*128] | rowptr int[N+1] | deg int[N]
    //   | eidx int[E] | bsum int[NB]
    char* ws = (char*)d_ws;
    size_t off = 0;
    bf16* hr     = (bf16*)(ws + off); off += (size_t)N * FEAT * 2;
    bf16* Wb     = (bf16*)(ws + off); off += (size_t)FEAT * FEAT * 2;
    int*  rowptr = (int*)(ws + off);  off += (size_t)(N + 1) * 4;
    int*  deg    = (int*)(ws + off);  off += (size_t)N * 4;
    int*  eidx   = (int*)(ws + off);  off += (size_t)E * 4;
    int*  bsum   = (int*)(ws + off);  off += (size_t)NB * 4;

    (void)hipMemsetAsync(deg, 0, (size_t)N * 4, stream);

    const int cbe = (E + 1023) / 1024;
    hist_wcvt_kernel<<<dim3(cbe + 4), dim3(256), 0, stream>>>(dst, deg, E, W, Wb, cbe);

    const int gb = (N + BM - 1) / BM;
    gemm_scanp_kernel<<<dim3(gb + NB), dim3(256), 0, stream>>>(
        h, Wb, b, hr, N, deg, bsum, N, gb);

    scan_bsums_kernel<<<dim3(1), dim3(256), 0, stream>>>(bsum, NB);
    scan_final_kernel<<<dim3(NB), dim3(256), 0, stream>>>(deg, bsum, rowptr, N, E);
    fill_kernel<<<dim3((E + 255) / 256), dim3(256), 0, stream>>>(src, dst, rowptr, deg, eidx, E);
    gather_kernel<<<dim3((N + 3) / 4), dim3(256), 0, stream>>>(hr, rowptr, eidx, out, N);
}